// Round 2
// baseline (83.694 us; speedup 1.0000x reference)
//
#include <hip/hip_runtime.h>

// SVF cascade frequency response on MI355X (gfx950) — R13 (= R12 resubmit;
// previous round died on container acquisition, not on the kernel).
//
// H(x) = (1+1j) * prod_k (b0*x^2+b1*x+b2)/(a0*x^2+a1*x+a2)
//
// Established: PLANAR output [Re H | Im H]; per-stage division (never
// reopen deferred — full-product dens overflow f32); coef delivery via
// d_ws; all stores guarded.
//
// R13: HEXADECIC fusion — 8 sections per stage, 8 stages of degree-16
// real-coefficient rationals. Division-block overhead halves (16 -> 8
// blocks, ~208 -> ~104 ops/sample) at +32 ops for powers x^9..x^16:
// ~745 -> ~674 ops/sample. The f32-range risk of degree-16 coefficients
// (tail samples |x|~5 push |den|^2 past 3.4e38) is removed EXACTLY by
// per-stage power-of-2 normalization: num and den coefs share one
// 2^-ilogb(max|den coef|) factor (f64, exact; ratio bit-identical), so
// |den(x)| <= ~5e12 and dd <= ~2.5e25 even at tails.
// Coef build stays f64 (sequential biquad convolution), rounded once to
// f32: 8*34 = 272 f32 = 1088 B in d_ws. Stage loop fully unrolled so
// uniform coef reads stay s_loads pipelined across stages.
// __launch_bounds__(256,4) caps VGPR at 128 (powers cost +32 regs vs
// octic; ~4 waves/SIMD retained).

#define NSEC  64
#define NHEX  8     // stages (8 fused biquads each)
#define DEG   16    // polynomial degree per stage
#define NCF   34    // 17 num + 17 den coefficients per stage
#define BLOCK 256
#define MPT   2     // samples per thread

// Pre-kernel: hexadecic coefficients in f64, normalized, stored f32.
// Layout (ascending powers): coef[t*34 + j]      = num coeff of x^j
//                            coef[t*34 + 17 + j] = den coeff of x^j
__global__ __launch_bounds__(64) void svf_coef_v13(
    const float* __restrict__ f_g,  const float* __restrict__ R_g,
    const float* __restrict__ lp_g, const float* __restrict__ bp_g,
    const float* __restrict__ hp_g,
    float* __restrict__ coef)
{
    const int t = threadIdx.x;
    if (t >= NHEX) return;

    double pn[DEG + 1], pd[DEG + 1];
    #pragma unroll
    for (int j = 0; j <= DEG; ++j) { pn[j] = 0.0; pd[j] = 0.0; }
    pn[0] = 1.0; pd[0] = 1.0;

    // Sequentially convolve 8 biquads (ascending-power convention:
    // num*x^2 = b2 + b1*x + b0*x^2, den*x^2 = a2 + a1*x + a0*x^2).
    #pragma unroll
    for (int s = 0; s < 8; ++s) {
        const int k = 8 * t + s;
        const double fk = (double)f_g[k],  Rk = (double)R_g[k];
        const double lp = (double)lp_g[k], bp = (double)bp_g[k], hp = (double)hp_g[k];
        const double f2 = fk * fk, fbp = fk * bp, flp = f2 * lp, rf2 = 2.0 * Rk * fk;
        const double bb0 = flp - fbp + hp;          // x^0 term (= b2)
        const double bb1 = 2.0 * flp - 2.0 * hp;    // x^1 term (= b1)
        const double bb2 = flp + fbp + hp;          // x^2 term (= b0)
        const double aa0 = f2 - rf2 + 1.0;
        const double aa1 = 2.0 * f2 - 2.0;
        const double aa2 = f2 + rf2 + 1.0;

        double nn[DEG + 1], nd[DEG + 1];
        #pragma unroll
        for (int j = 0; j <= DEG; ++j) { nn[j] = 0.0; nd[j] = 0.0; }
        #pragma unroll
        for (int i = 0; i <= DEG - 2; ++i) {   // pn[i]=0 beyond current deg
            nn[i]     += pn[i] * bb0;
            nn[i + 1] += pn[i] * bb1;
            nn[i + 2] += pn[i] * bb2;
            nd[i]     += pd[i] * aa0;
            nd[i + 1] += pd[i] * aa1;
            nd[i + 2] += pd[i] * aa2;
        }
        #pragma unroll
        for (int j = 0; j <= DEG; ++j) { pn[j] = nn[j]; pd[j] = nd[j]; }
    }

    // Power-of-2 normalization: same factor on num and den -> ratio is
    // EXACTLY preserved; den coefs land in [~2^-5, 1), keeping the f32
    // evaluation and |den|^2 far from overflow/denormal at |x| tails.
    double mx = 0.0;
    #pragma unroll
    for (int j = 0; j <= DEG; ++j) mx = fmax(mx, fabs(pd[j]));
    const double sc = (mx > 0.0) ? ldexp(1.0, -ilogb(mx)) : 1.0;

    float* cp = coef + t * NCF;
    #pragma unroll
    for (int j = 0; j <= DEG; ++j) {
        cp[j]          = (float)(pn[j] * sc);
        cp[17 + j]     = (float)(pd[j] * sc);
    }
}

// complex square / multiply helpers (fma-contracted)
#define CSQ(dr_, di_, ar_, ai_)                                   \
    dr_ = fmaf((ar_), (ar_), -((ai_) * (ai_)));                   \
    di_ = 2.0f * ((ar_) * (ai_));
#define CMUL(dr_, di_, ar_, ai_, br_, bi_)                        \
    dr_ = fmaf((ar_), (br_), -((ai_) * (bi_)));                   \
    di_ = fmaf((ar_), (bi_),  ((ai_) * (br_)));

__global__ __launch_bounds__(BLOCK, 4) void svf_f32_v13(
    const float* __restrict__ xr_g, const float* __restrict__ xi_g,
    const float* __restrict__ coef,
    float* __restrict__ out, int n, long long cap_floats)
{
    const int t = threadIdx.x;
    const long long base = (long long)(blockIdx.x * BLOCK + t) * MPT;

    // Xr[q-1][m], Xi[q-1][m] hold x^q for q = 1..16. All indexing is
    // compile-time (full unroll) -> stays in VGPRs, no scratch.
    float Xr[16][MPT], Xi[16][MPT];
    float Hr[MPT], Hi[MPT];

    if (base + MPT <= (long long)n) {
        const float2 a = *reinterpret_cast<const float2*>(xr_g + base);
        const float2 b = *reinterpret_cast<const float2*>(xi_g + base);
        Xr[0][0] = a.x; Xr[0][1] = a.y;
        Xi[0][0] = b.x; Xi[0][1] = b.y;
    } else {
        for (int m = 0; m < MPT; ++m) {
            const long long idx = base + m;
            const bool ok = idx < (long long)n;
            Xr[0][m] = ok ? xr_g[idx] : 1.0f;
            Xi[0][m] = ok ? xi_g[idx] : 0.0f;
        }
    }

    #pragma unroll
    for (int m = 0; m < MPT; ++m) {
        // powers x^2..x^16: 8 squarings + 7 general mults, spread for ILP
        CSQ (Xr[1][m],  Xi[1][m],  Xr[0][m], Xi[0][m]);                       // x^2
        CMUL(Xr[2][m],  Xi[2][m],  Xr[1][m], Xi[1][m], Xr[0][m], Xi[0][m]);   // x^3
        CSQ (Xr[3][m],  Xi[3][m],  Xr[1][m], Xi[1][m]);                       // x^4
        CMUL(Xr[4][m],  Xi[4][m],  Xr[3][m], Xi[3][m], Xr[0][m], Xi[0][m]);   // x^5
        CSQ (Xr[5][m],  Xi[5][m],  Xr[2][m], Xi[2][m]);                       // x^6
        CMUL(Xr[6][m],  Xi[6][m],  Xr[3][m], Xi[3][m], Xr[2][m], Xi[2][m]);   // x^7
        CSQ (Xr[7][m],  Xi[7][m],  Xr[3][m], Xi[3][m]);                       // x^8
        CMUL(Xr[8][m],  Xi[8][m],  Xr[7][m], Xi[7][m], Xr[0][m], Xi[0][m]);   // x^9
        CSQ (Xr[9][m],  Xi[9][m],  Xr[4][m], Xi[4][m]);                       // x^10
        CMUL(Xr[10][m], Xi[10][m], Xr[7][m], Xi[7][m], Xr[2][m], Xi[2][m]);   // x^11
        CSQ (Xr[11][m], Xi[11][m], Xr[5][m], Xi[5][m]);                       // x^12
        CMUL(Xr[12][m], Xi[12][m], Xr[7][m], Xi[7][m], Xr[4][m], Xi[4][m]);   // x^13
        CSQ (Xr[13][m], Xi[13][m], Xr[6][m], Xi[6][m]);                       // x^14
        CMUL(Xr[14][m], Xi[14][m], Xr[7][m], Xi[7][m], Xr[6][m], Xi[6][m]);   // x^15
        CSQ (Xr[15][m], Xi[15][m], Xr[7][m], Xi[7][m]);                       // x^16
        Hr[m] = 1.0f;   // H starts at (1 + 1j)
        Hi[m] = 1.0f;
    }

    #pragma unroll
    for (int p = 0; p < NHEX; ++p) {
        // Loop-uniform -> s_load; full unroll pipelines coef loads
        // across stages.
        const float* cp = coef + p * NCF;
        float cn[17], cd[17];
        #pragma unroll
        for (int j = 0; j < 17; ++j) { cn[j] = cp[j]; cd[j] = cp[17 + j]; }

        #pragma unroll
        for (int m = 0; m < MPT; ++m) {
            // num/den hexadecic: real coefs (ascending powers) dotted
            // against precomputed complex powers. 4 independent 16-fma
            // chains (x2 samples) keep the SIMD issue port fed.
            float nr = cn[0], ni = 0.0f, dr = cd[0], di = 0.0f;
            #pragma unroll
            for (int q = 1; q <= 16; ++q) {
                nr = fmaf(cn[q], Xr[q - 1][m], nr);
                ni = fmaf(cn[q], Xi[q - 1][m], ni);
                dr = fmaf(cd[q], Xr[q - 1][m], dr);
                di = fmaf(cd[q], Xi[q - 1][m], di);
            }
            // ratio = num * conj(den) / |den|^2 (per-stage division)
            const float dd  = fmaf(dr, dr, di * di);
            const float inv = __builtin_amdgcn_rcpf(dd);   // ~1e-7 rel x 8, ok
            const float tr  = fmaf(nr, dr,   ni * di);
            const float ti  = fmaf(ni, dr, -(nr * di));
            const float rr  = tr * inv;
            const float ri  = ti * inv;
            // H *= ratio
            const float hr = fmaf(Hr[m], rr, -(Hi[m] * ri));
            const float hi = fmaf(Hr[m], ri,   Hi[m] * rr);
            Hr[m] = hr; Hi[m] = hi;
        }
    }

    // PLANAR output: out[0..n-1] = Re H, out[n..2n-1] = Im H. Guarded.
    const long long imag_off = (long long)n;
    if (base + MPT <= (long long)n && 2LL * (long long)n <= cap_floats) {
        float2 vr, vi;
        vr.x = Hr[0]; vr.y = Hr[1];
        vi.x = Hi[0]; vi.y = Hi[1];
        *reinterpret_cast<float2*>(out + base)            = vr;
        *reinterpret_cast<float2*>(out + imag_off + base) = vi;
    } else {
        for (int m = 0; m < MPT; ++m) {
            const long long idx = base + m;
            if (idx < (long long)n) {
                if (idx + 1 <= cap_floats) out[idx] = Hr[m];
                const long long oi = imag_off + idx;
                if (oi + 1 <= cap_floats) out[oi] = Hi[m];
            }
        }
    }
}

extern "C" void kernel_launch(void* const* d_in, const int* in_sizes, int n_in,
                              void* d_out, int out_size, void* d_ws, size_t ws_size,
                              hipStream_t stream) {
    const float* xr = (const float*)d_in[0];
    const float* xi = (const float*)d_in[1];
    const float* f  = (const float*)d_in[2];
    const float* R  = (const float*)d_in[3];
    const float* lp = (const float*)d_in[4];
    const float* bp = (const float*)d_in[5];
    const float* hp = (const float*)d_in[6];
    float* out = (float*)d_out;
    float* coef = (float*)d_ws;   // 8*34*4 = 1088 B of scratch

    const int n = in_sizes[0];  // 1048576
    long long cap = (long long)out_size;
    if (cap > 2LL * (long long)n) cap = 2LL * (long long)n;

    // Stage 1: hexadecic coefficients (f64 math, pow2-normalized, f32 store).
    svf_coef_v13<<<1, 64, 0, stream>>>(f, R, lp, bp, hp, coef);
    // Stage 2: main sweep, all-f32, 8 fully-unrolled degree-16 stages.
    const int grid = (n + BLOCK * MPT - 1) / (BLOCK * MPT);  // 2048
    svf_f32_v13<<<grid, BLOCK, 0, stream>>>(xr, xi, coef, out, n, cap);
}